// Round 2
// baseline (134.424 us; speedup 1.0000x reference)
//
#include <hip/hip_runtime.h>
#include <hip/hip_bf16.h>
#include <stdint.h>

// (B,SQ,SV,D) = (4,4096,4096,64), fp32 in/out.
// Flash attention via bf16 MFMA with 3-term hi/lo split on both matmuls.
// S' = V.Q^T (swapped) so P lands in the PV B-operand layout in-register;
// V row-storage is permuted (phi) so P's k-slots are contiguous (v = 8*lg+i).
#define BATCH 4
#define SQN   4096
#define SVN   4096
#define DIM   64
#define KT    32               // keys per tile
#define NTILE (SVN / KT)       // 128 tiles per batch
#define NSTEP 32               // tiles per SV-quarter (1024/32)

// Prepared-V blob: 4 LDS-image planes. RM planes hold PERMUTED rows
// (storage row p holds V row phi(p)); TR planes hold true-v columns.
#define RMS 72                 // row-major stride (elems): 144B rows
#define TRS 40                 // transposed stride (elems): 80B rows, 16B-aligned b128
#define IMG_RM_H 0
#define IMG_RM_L 4608
#define IMG_TR_H 9216
#define IMG_TR_L 14336
#define BLOB     19456         // = 19 x 1024B chunks
#define NCHUNK   19
#define LDS_BYTES (8 * BLOB)   // 4 quarters x 2 buffers = 155648 B (<160 KiB)

typedef __attribute__((ext_vector_type(8))) short bf16x8;
typedef __attribute__((ext_vector_type(4))) float f32x4;
typedef __attribute__((ext_vector_type(4))) unsigned int u32x4;

#if __has_builtin(__builtin_amdgcn_exp2f)
#define EXP2F __builtin_amdgcn_exp2f
#else
#define EXP2F exp2f
#endif

static __device__ __forceinline__ unsigned short bf16_rne(float x) {
  unsigned u = __float_as_uint(x);
  u += 0x7FFFu + ((u >> 16) & 1u);
  return (unsigned short)(u >> 16);
}
static __device__ __forceinline__ float bf16f(unsigned short h) {
  return __uint_as_float((unsigned)h << 16);
}
// v_cvt_pk_bf16_f32: dword = {bf16(lo) in [15:0], bf16(hi) in [31:16]}
static __device__ __forceinline__ unsigned cvt_pk_bf16(float lo, float hi) {
  unsigned r;
  asm("v_cvt_pk_bf16_f32 %0, %1, %2" : "=v"(r) : "v"(lo), "v"(hi));
  return r;
}

// ---------------------------------------------------------------------------
// Prep: V fp32 -> per-tile blobs in ws via LDS (coalesced global writes).
// grid = 4*128 blocks x 256 thr; each block = one 32-key tile.
// ---------------------------------------------------------------------------
__global__ __launch_bounds__(256) void vprep_kernel(const float* __restrict__ V,
                                                    char* __restrict__ ws) {
  __shared__ __align__(16) char sbuf[BLOB];
  const int b    = blockIdx.x >> 7;
  const int tile = blockIdx.x & 127;
  const int t    = threadIdx.x;
  const int vv   = t >> 3;          // 0..31 key within tile
  const int d0   = (t & 7) * 8;     // 0..56 feature chunk

  const float* src = V + (((size_t)b * SVN + (size_t)tile * KT + vv) * DIM + d0);
  const float4 a0 = ((const float4*)src)[0];
  const float4 a1 = ((const float4*)src)[1];
  const float x[8] = {a0.x, a0.y, a0.z, a0.w, a1.x, a1.y, a1.z, a1.w};

  unsigned short h[8], l[8];
#pragma unroll
  for (int j = 0; j < 8; ++j) {
    h[j] = bf16_rne(x[j]);
    l[j] = bf16_rne(x[j] - bf16f(h[j]));
  }

  // storage row p: phi(p<16)=8*(p>>2)+(p&3); phi(p>=16)=that+4  (p=phi^-1(vv))
  const int p = (((vv >> 2) & 1) << 4) | ((vv >> 3) << 2) | (vv & 3);
  bf16x8 vh, vl;
#pragma unroll
  for (int j = 0; j < 8; ++j) { vh[j] = (short)h[j]; vl[j] = (short)l[j]; }
  *(bf16x8*)(sbuf + IMG_RM_H + (p * RMS + d0) * 2) = vh;
  *(bf16x8*)(sbuf + IMG_RM_L + (p * RMS + d0) * 2) = vl;

  unsigned short* trh = (unsigned short*)(sbuf + IMG_TR_H);
  unsigned short* trl = (unsigned short*)(sbuf + IMG_TR_L);
#pragma unroll
  for (int j = 0; j < 8; ++j) {
    trh[(d0 + j) * TRS + vv] = h[j];
    trl[(d0 + j) * TRS + vv] = l[j];
  }
  __syncthreads();

  // coalesced copy-out: 19456/16 = 1216 float4
  float4* dst = (float4*)(ws + (size_t)(b * NTILE + tile) * BLOB);
  const float4* s4 = (const float4*)sbuf;
#pragma unroll
  for (int k = 0; k < 5; ++k) {
    const int idx = t + k * 256;
    if (idx < BLOB / 16) dst[idx] = s4[idx];
  }
}

// ---------------------------------------------------------------------------
// Main: 256 blocks x 512 thr. Block = 64 q-rows of one batch.
// wave w: qt = w&1 (32-q half), quarter = w>>1 (1024-key span). 4-way merge.
// ---------------------------------------------------------------------------
__global__ __launch_bounds__(512, 2) void attn_kernel(const float* __restrict__ Qg,
                                                      const char* __restrict__ vprep,
                                                      float* __restrict__ out) {
  extern __shared__ char smem[];
  const int raw = blockIdx.x;
  const int lb = (raw & 7) * 32 + (raw >> 3);  // XCD swizzle: 2 XCDs per batch
  const int batch = lb >> 6;
  const int qbase = (lb & 63) * 64;
  const int tid = threadIdx.x;
  const int lane = tid & 63;
  const int wid = tid >> 6;
  const int qt = wid & 1;
  const int quarter = wid >> 1;
  const int lr = lane & 15;
  const int lg = lane >> 4;

  // ---- Q fragments (x log2e), hi/lo split; B slot (lg,i) <-> d = ks*32+8lg+i
  bf16x8 Qh[2][2], Ql[2][2];
#pragma unroll
  for (int qb = 0; qb < 2; ++qb) {
    const size_t qrow = (size_t)batch * SQN + qbase + qt * 32 + qb * 16 + lr;
#pragma unroll
    for (int ks = 0; ks < 2; ++ks) {
      const float* qp = Qg + qrow * DIM + ks * 32 + 8 * lg;
      const float4 f0 = ((const float4*)qp)[0];
      const float4 f1 = ((const float4*)qp)[1];
      const float xv[8] = {f0.x, f0.y, f0.z, f0.w, f1.x, f1.y, f1.z, f1.w};
#pragma unroll
      for (int j = 0; j < 8; ++j) {
        const float v = xv[j] * 1.44269504088896f;
        const unsigned short hh = bf16_rne(v);
        Qh[qb][ks][j] = (short)hh;
        Ql[qb][ks][j] = (short)bf16_rne(v - bf16f(hh));
      }
    }
  }

  f32x4 Oacc[2][4];
#pragma unroll
  for (int qb = 0; qb < 2; ++qb)
#pragma unroll
    for (int db = 0; db < 4; ++db) Oacc[qb][db] = (f32x4){0.f, 0.f, 0.f, 0.f};
  float m_[2] = {-1e30f, -1e30f};
  float l_[2] = {0.f, 0.f};

  const size_t tb0 = (size_t)(batch * NTILE) * BLOB;
  const int sq = wid >> 1;   // quarter this wave stages (= its compute quarter)
  const int sh = wid & 1;

  auto stage = [&](int t, int b) {
#pragma unroll
    for (int k = 0; k < 10; ++k) {
      const int sub = sh + 2 * k;
      if (sub < NCHUNK) {
        const char* g = vprep + tb0 + (size_t)(sq * NSTEP + t) * BLOB + sub * 1024 + lane * 16;
        char* lp = smem + (sq * 2 + b) * BLOB + sub * 1024;  // wave-uniform base
        __builtin_amdgcn_global_load_lds(
            (const __attribute__((address_space(1))) unsigned int*)g,
            (__attribute__((address_space(3))) unsigned int*)lp, 16, 0, 0);
      }
    }
  };

  stage(0, 0);
  __syncthreads();
  int buf = 0;

  for (int t = 0; t < NSTEP; ++t) {
    if (t + 1 < NSTEP) stage(t + 1, buf ^ 1);

    const char* qbuf = smem + (quarter * 2 + buf) * BLOB;

    // V (A of S'): storage rows vt*16+lr, k-slot = ks*32 + 8lg + i
    bf16x8 Vh[2][2], Vl[2][2];
#pragma unroll
    for (int vt = 0; vt < 2; ++vt)
#pragma unroll
      for (int ks = 0; ks < 2; ++ks) {
        const int off = ((vt * 16 + lr) * RMS + ks * 32 + 8 * lg) * 2;
        Vh[vt][ks] = *(const bf16x8*)(qbuf + IMG_RM_H + off);
        Vl[vt][ks] = *(const bf16x8*)(qbuf + IMG_RM_L + off);
      }

    // S' = V.Q^T (3-term). Output: lane holds P[v = 8lg + 4vt + r][q = lr]
    f32x4 sacc[2][2];
#pragma unroll
    for (int qb = 0; qb < 2; ++qb)
#pragma unroll
      for (int vt = 0; vt < 2; ++vt) {
        f32x4 acc = (f32x4){0.f, 0.f, 0.f, 0.f};
#pragma unroll
        for (int ks = 0; ks < 2; ++ks) {
          acc = __builtin_amdgcn_mfma_f32_16x16x32_bf16(Vh[vt][ks], Qh[qb][ks], acc, 0, 0, 0);
          acc = __builtin_amdgcn_mfma_f32_16x16x32_bf16(Vh[vt][ks], Ql[qb][ks], acc, 0, 0, 0);
          acc = __builtin_amdgcn_mfma_f32_16x16x32_bf16(Vl[vt][ks], Qh[qb][ks], acc, 0, 0, 0);
        }
        sacc[qb][vt] = acc;
      }

    // online softmax (log2 domain); p[i] <-> v = 8lg + i = PV B k-slot i
    bf16x8 Ph[2], Pl[2];
#pragma unroll
    for (int qb = 0; qb < 2; ++qb) {
      float mt = -1e30f;
#pragma unroll
      for (int vt = 0; vt < 2; ++vt)
#pragma unroll
        for (int r = 0; r < 4; ++r) mt = fmaxf(mt, sacc[qb][vt][r]);
      mt = fmaxf(mt, __shfl_xor(mt, 16, 64));
      mt = fmaxf(mt, __shfl_xor(mt, 32, 64));
      const float mnew = fmaxf(m_[qb], mt);
      const float alpha = EXP2F(m_[qb] - mnew);
      float p[8];
      float rs = 0.f;
#pragma unroll
      for (int vt = 0; vt < 2; ++vt)
#pragma unroll
        for (int r = 0; r < 4; ++r) {
          const float pv = EXP2F(sacc[qb][vt][r] - mnew);
          p[vt * 4 + r] = pv;
          rs += pv;
        }
      rs += __shfl_xor(rs, 16, 64);
      rs += __shfl_xor(rs, 32, 64);
      l_[qb] = l_[qb] * alpha + rs;
      m_[qb] = mnew;
#pragma unroll
      for (int db = 0; db < 4; ++db) Oacc[qb][db] *= alpha;
      // hi/lo bf16 pack via v_cvt_pk_bf16_f32
      u32x4 hu, lu;
#pragma unroll
      for (int j = 0; j < 4; ++j) {
        const unsigned hd = cvt_pk_bf16(p[2 * j], p[2 * j + 1]);
        const float h0 = __uint_as_float(hd << 16);
        const float h1 = __uint_as_float(hd & 0xFFFF0000u);
        hu[j] = hd;
        lu[j] = cvt_pk_bf16(p[2 * j] - h0, p[2 * j + 1] - h1);
      }
      Ph[qb] = __builtin_bit_cast(bf16x8, hu);
      Pl[qb] = __builtin_bit_cast(bf16x8, lu);
    }

    // PV: O'[d][q] += V^T.P' — A slot (lg,i) = V[8lg+i][d], contiguous b128
#pragma unroll
    for (int db = 0; db < 4; ++db) {
      const int toff = ((db * 16 + lr) * TRS + 8 * lg) * 2;
      const bf16x8 Ah = *(const bf16x8*)(qbuf + IMG_TR_H + toff);
      const bf16x8 Al = *(const bf16x8*)(qbuf + IMG_TR_L + toff);
#pragma unroll
      for (int qb = 0; qb < 2; ++qb) {
        Oacc[qb][db] = __builtin_amdgcn_mfma_f32_16x16x32_bf16(Ah, Ph[qb], Oacc[qb][db], 0, 0, 0);
        Oacc[qb][db] = __builtin_amdgcn_mfma_f32_16x16x32_bf16(Al, Ph[qb], Oacc[qb][db], 0, 0, 0);
        Oacc[qb][db] = __builtin_amdgcn_mfma_f32_16x16x32_bf16(Ah, Pl[qb], Oacc[qb][db], 0, 0, 0);
      }
    }

    __syncthreads();
    buf ^= 1;
  }

  // ---- 4-way quarter merge through LDS (reuses staging region) ----
  float* mbuf = (float*)smem;                          // [2][4][32][68]
  float* mlb  = (float*)(smem + 2 * 4 * 32 * 68 * 4);  // [2][4][32][2]
#pragma unroll
  for (int qb = 0; qb < 2; ++qb) {
    const int q = qb * 16 + lr;
    float* dst = mbuf + ((qt * 4 + quarter) * 32 + q) * 68;
#pragma unroll
    for (int db = 0; db < 4; ++db)
#pragma unroll
      for (int r = 0; r < 4; ++r) dst[db * 16 + 4 * lg + r] = Oacc[qb][db][r];
  }
  if (lg == 0) {
#pragma unroll
    for (int qb = 0; qb < 2; ++qb) {
      const int q = qb * 16 + lr;
      mlb[((qt * 4 + quarter) * 32 + q) * 2 + 0] = m_[qb];
      mlb[((qt * 4 + quarter) * 32 + q) * 2 + 1] = l_[qb];
    }
  }
  __syncthreads();

  const int q_all = tid >> 3;        // 0..63
  const int d0 = (tid & 7) * 8;
  const int qt2 = q_all >> 5;
  const int qq = q_all & 31;
  float M = -1e30f;
#pragma unroll
  for (int w = 0; w < 4; ++w) M = fmaxf(M, mlb[((qt2 * 4 + w) * 32 + qq) * 2]);
  float L = 0.f;
  float o[8] = {0, 0, 0, 0, 0, 0, 0, 0};
#pragma unroll
  for (int w = 0; w < 4; ++w) {
    const float a = EXP2F(mlb[((qt2 * 4 + w) * 32 + qq) * 2] - M);
    L += a * mlb[((qt2 * 4 + w) * 32 + qq) * 2 + 1];
    const float* srcp = mbuf + ((qt2 * 4 + w) * 32 + qq) * 68 + d0;
#pragma unroll
    for (int j = 0; j < 8; ++j) o[j] += a * srcp[j];
  }
  const float inv = 1.0f / L;
  float* op = out + ((size_t)batch * SQN + qbase + qt2 * 32 + qq) * DIM + d0;
  float4 w0 = {o[0] * inv, o[1] * inv, o[2] * inv, o[3] * inv};
  float4 w1 = {o[4] * inv, o[5] * inv, o[6] * inv, o[7] * inv};
  ((float4*)op)[0] = w0;
  ((float4*)op)[1] = w1;
}

// ---------------------------------------------------------------------------
extern "C" void kernel_launch(void* const* d_in, const int* in_sizes, int n_in,
                              void* d_out, int out_size, void* d_ws, size_t ws_size,
                              hipStream_t stream) {
  const float* Qg = (const float*)d_in[0];
  const float* Vg = (const float*)d_in[1];
  float* out = (float*)d_out;
  char* ws = (char*)d_ws;
  const size_t need = (size_t)BATCH * NTILE * BLOB;  // 9.96 MB
  if (ws_size < need) return;  // cannot run without scratch

  hipFuncSetAttribute((const void*)attn_kernel,
                      hipFuncAttributeMaxDynamicSharedMemorySize, LDS_BYTES);

  vprep_kernel<<<BATCH * NTILE, 256, 0, stream>>>(Vg, ws);
  attn_kernel<<<256, 512, LDS_BYTES, stream>>>(Qg, ws, out);
}